// Round 6
// baseline (1791.037 us; speedup 1.0000x reference)
//
#include <hip/hip_runtime.h>

#define N_IN   100000
#define N_OUT  400000
#define KK     8
#define PP     100000
#define C_IN   128
#define C_OUTC 64
#define C_SKIP 64
#define EPS_BN 1e-5f

// ---------------------------------------------------------------------------
// One-time: build interleaved weights wq[k][iq][c] = float4(W[k][4iq..4iq+3][c])
// so the scatter kernel's per-lane weight read is one coalesced dwordx4.
// ---------------------------------------------------------------------------
__global__ __launch_bounds__(256) void prep_w(
    const float* __restrict__ Wd, float4* __restrict__ wq)
{
    const int e = blockIdx.x * 256 + threadIdx.x;   // over KK*C_IN*C_OUTC
    if (e < KK * C_IN * C_OUTC) {
        const int k = e >> 13;                      // / (C_IN*C_OUTC)
        const int r = e & (C_IN * C_OUTC - 1);
        const int i = r >> 6, c = r & 63;
        ((float*)&wq[((size_t)k * 32 + (i >> 2)) * C_OUTC + c])[i & 3] = Wd[e];
    }
}

// ---------------------------------------------------------------------------
// Scatter: y[out_idx] += x[in_idx] @ W_deconv[k]
// Round-1 shape, fixed: NO LDS, no barriers, 256-thr blocks, 2048 blocks
// (8192 waves -> max TLP; the kernel is L2/L3-latency-bound on the
// per-lane-uniform x broadcasts, so occupancy is the lever). Weights come
// from the interleaved wq copy: one coalesced 16B/lane load per 4 input
// channels, L1-resident (32 KB per k, k uniform per block). 8 pairs per
// group amortize weight loads; atomics issued per group (round-1 cadence).
// ---------------------------------------------------------------------------
__global__ __launch_bounds__(256, 6) void scatter_kernel(
    const float* __restrict__ x, const float4* __restrict__ wq,
    const int* __restrict__ in_idx, const int* __restrict__ out_idx,
    float* __restrict__ y)
{
    const int k    = blockIdx.y;
    const int lane = threadIdx.x & 63;
    const int wv   = (int)((blockIdx.x * 256 + threadIdx.x) >> 6);
    const int nw   = (int)gridDim.x * 4;
    const int4* __restrict__ ii4 = (const int4*)(in_idx + k * PP);
    const int4* __restrict__ oi4 = (const int4*)(out_idx + k * PP);
    const float4* __restrict__ wk = wq + (size_t)k * (32 * C_OUTC) + lane;

    for (int g = wv; g < PP / 8; g += nw) {
        const int4 ia = ii4[2 * g], ib = ii4[2 * g + 1];
        const float4* __restrict__ x0 = (const float4*)(x + (size_t)ia.x * C_IN);
        const float4* __restrict__ x1 = (const float4*)(x + (size_t)ia.y * C_IN);
        const float4* __restrict__ x2 = (const float4*)(x + (size_t)ia.z * C_IN);
        const float4* __restrict__ x3 = (const float4*)(x + (size_t)ia.w * C_IN);
        const float4* __restrict__ x4 = (const float4*)(x + (size_t)ib.x * C_IN);
        const float4* __restrict__ x5 = (const float4*)(x + (size_t)ib.y * C_IN);
        const float4* __restrict__ x6 = (const float4*)(x + (size_t)ib.z * C_IN);
        const float4* __restrict__ x7 = (const float4*)(x + (size_t)ib.w * C_IN);

        float a0=0.f,a1=0.f,a2=0.f,a3=0.f,a4=0.f,a5=0.f,a6=0.f,a7=0.f;
        #pragma unroll 4
        for (int iq = 0; iq < C_IN / 4; ++iq) {
            const float4 w4 = wk[iq * C_OUTC];          // coalesced, L1-hot
            const float4 v0 = x0[iq]; const float4 v1 = x1[iq];
            const float4 v2 = x2[iq]; const float4 v3 = x3[iq];
            const float4 v4 = x4[iq]; const float4 v5 = x5[iq];
            const float4 v6 = x6[iq]; const float4 v7 = x7[iq];
            a0 = fmaf(v0.x, w4.x, a0); a0 = fmaf(v0.y, w4.y, a0);
            a0 = fmaf(v0.z, w4.z, a0); a0 = fmaf(v0.w, w4.w, a0);
            a1 = fmaf(v1.x, w4.x, a1); a1 = fmaf(v1.y, w4.y, a1);
            a1 = fmaf(v1.z, w4.z, a1); a1 = fmaf(v1.w, w4.w, a1);
            a2 = fmaf(v2.x, w4.x, a2); a2 = fmaf(v2.y, w4.y, a2);
            a2 = fmaf(v2.z, w4.z, a2); a2 = fmaf(v2.w, w4.w, a2);
            a3 = fmaf(v3.x, w4.x, a3); a3 = fmaf(v3.y, w4.y, a3);
            a3 = fmaf(v3.z, w4.z, a3); a3 = fmaf(v3.w, w4.w, a3);
            a4 = fmaf(v4.x, w4.x, a4); a4 = fmaf(v4.y, w4.y, a4);
            a4 = fmaf(v4.z, w4.z, a4); a4 = fmaf(v4.w, w4.w, a4);
            a5 = fmaf(v5.x, w4.x, a5); a5 = fmaf(v5.y, w4.y, a5);
            a5 = fmaf(v5.z, w4.z, a5); a5 = fmaf(v5.w, w4.w, a5);
            a6 = fmaf(v6.x, w4.x, a6); a6 = fmaf(v6.y, w4.y, a6);
            a6 = fmaf(v6.z, w4.z, a6); a6 = fmaf(v6.w, w4.w, a6);
            a7 = fmaf(v7.x, w4.x, a7); a7 = fmaf(v7.y, w4.y, a7);
            a7 = fmaf(v7.z, w4.z, a7); a7 = fmaf(v7.w, w4.w, a7);
        }
        const int4 oa = oi4[2 * g], ob = oi4[2 * g + 1];
        atomicAdd(&y[(size_t)oa.x * C_OUTC + lane], a0);
        atomicAdd(&y[(size_t)oa.y * C_OUTC + lane], a1);
        atomicAdd(&y[(size_t)oa.z * C_OUTC + lane], a2);
        atomicAdd(&y[(size_t)oa.w * C_OUTC + lane], a3);
        atomicAdd(&y[(size_t)ob.x * C_OUTC + lane], a4);
        atomicAdd(&y[(size_t)ob.y * C_OUTC + lane], a5);
        atomicAdd(&y[(size_t)ob.z * C_OUTC + lane], a6);
        atomicAdd(&y[(size_t)ob.w * C_OUTC + lane], a7);
    }
}

// ---------------------------------------------------------------------------
// Per-channel sum / sumsq over y (float4 per thread) -> stats[0:64] | [64:128]
// ---------------------------------------------------------------------------
__global__ __launch_bounds__(256) void stats_kernel(
    const float* __restrict__ y, float* __restrict__ stats)
{
    const int tid = threadIdx.x;
    const int cq  = tid & 15;                          // channel quad 0..15
    const int rid = (int)((blockIdx.x * 256 + tid) >> 4);
    const int nr  = (int)(gridDim.x * 256) >> 4;
    const float4* __restrict__ y4 = (const float4*)y;

    float sx=0,sy=0,sz=0,sw=0, qx=0,qy=0,qz=0,qw=0;
    for (int r = rid; r < N_OUT; r += nr) {
        const float4 v = y4[(size_t)r * 16 + cq];
        sx += v.x; sy += v.y; sz += v.z; sw += v.w;
        qx = fmaf(v.x, v.x, qx); qy = fmaf(v.y, v.y, qy);
        qz = fmaf(v.z, v.z, qz); qw = fmaf(v.w, v.w, qw);
    }
    __shared__ float ls[4 * 256];
    __shared__ float lq[4 * 256];
    ls[0*256+tid]=sx; ls[1*256+tid]=sy; ls[2*256+tid]=sz; ls[3*256+tid]=sw;
    lq[0*256+tid]=qx; lq[1*256+tid]=qy; lq[2*256+tid]=qz; lq[3*256+tid]=qw;
    __syncthreads();
    for (int off = 128; off >= 16; off >>= 1) {
        if (tid < off) {
            #pragma unroll
            for (int c = 0; c < 4; ++c) {
                ls[c*256+tid] += ls[c*256+tid+off];
                lq[c*256+tid] += lq[c*256+tid+off];
            }
        }
        __syncthreads();
    }
    if (tid < 16) {
        #pragma unroll
        for (int c = 0; c < 4; ++c) {
            atomicAdd(&stats[tid * 4 + c],           ls[c*256+tid]);
            atomicAdd(&stats[C_OUTC + tid * 4 + c],  lq[c*256+tid]);
        }
    }
}

// ---------------------------------------------------------------------------
// Fold BN into fuse-friendly constants.
//  s[i]   = gamma*rsqrt(var+eps)          (sc[0:64])
//  nb[i]  = -(beta - mean*s)/s            (sc[64:128])
//  bias[c]= sum_i b_i * Wf[i][c]          (sc[128:192])
// relu(y*s+b) @ W = max(y, -b/s) @ (diag(s)W) + (b @ W), s > 0.
// ---------------------------------------------------------------------------
__global__ void finalize_kernel(const float* __restrict__ stats,
                                const float* __restrict__ gamma,
                                const float* __restrict__ beta,
                                const float* __restrict__ Wf,
                                float* __restrict__ sc)
{
    __shared__ float bsh[C_OUTC];
    const int c = threadIdx.x;                 // 64 threads
    const float inv_n = 1.0f / (float)N_OUT;
    const float mean  = stats[c] * inv_n;
    const float var   = stats[C_OUTC + c] * inv_n - mean * mean;
    const float s     = gamma[c] * rsqrtf(var + EPS_BN);
    const float b     = beta[c] - mean * s;
    sc[c]            = s;
    sc[C_OUTC + c]   = -b / s;
    bsh[c] = b;
    __syncthreads();
    float acc = 0.f;
    for (int i = 0; i < C_OUTC; ++i)
        acc = fmaf(bsh[i], Wf[i * C_OUTC + c], acc);
    sc[2 * C_OUTC + c] = acc;
}

// ---------------------------------------------------------------------------
// Fused BN+ReLU+concat+linear, in-place on y (unchanged from round 4).
// ---------------------------------------------------------------------------
__global__ __launch_bounds__(512) void fuse_kernel(
    float* __restrict__ y, const float* __restrict__ skip,
    const float* __restrict__ Wf, const float* __restrict__ sc)
{
    __shared__ float wlds[C_IN * C_OUTC];          // [i][c], y-half pre-scaled
    __shared__ float nb[C_OUTC];
    for (int e = threadIdx.x; e < C_IN * C_OUTC; e += 512) {
        const int i = e >> 6;
        const float w = Wf[e];
        wlds[e] = (i < C_OUTC) ? w * sc[i] : w;
    }
    if (threadIdx.x < C_OUTC) nb[threadIdx.x] = sc[C_OUTC + threadIdx.x];
    __syncthreads();

    const int lane = threadIdx.x & 63;
    int wv = (int)((blockIdx.x * 512 + threadIdx.x) >> 6);
    wv = __builtin_amdgcn_readfirstlane(wv);       // SGPR wave id -> s_load rows
    const int nw = (int)gridDim.x * 8;
    const float bias0 = sc[2 * C_OUTC + lane];

    for (int g = wv; g < N_OUT / 8; g += nw) {
        const float* __restrict__ yr = y    + (size_t)g * 8 * C_OUTC;
        const float* __restrict__ sr = skip + (size_t)g * 8 * C_SKIP;

        float acc[8];
        #pragma unroll
        for (int r = 0; r < 8; ++r) acc[r] = bias0;

        #pragma unroll 8
        for (int i = 0; i < C_OUTC; ++i) {
            const float w = wlds[i * C_OUTC + lane];
            const float t = nb[i];
            #pragma unroll
            for (int r = 0; r < 8; ++r)
                acc[r] = fmaf(fmaxf(yr[r * C_OUTC + i], t), w, acc[r]);
        }
        #pragma unroll 8
        for (int i = 0; i < C_SKIP; ++i) {
            const float w = wlds[(C_OUTC + i) * C_OUTC + lane];
            #pragma unroll
            for (int r = 0; r < 8; ++r)
                acc[r] = fmaf(sr[r * C_SKIP + i], w, acc[r]);
        }
        #pragma unroll
        for (int r = 0; r < 8; ++r)
            y[((size_t)g * 8 + r) * C_OUTC + lane] = acc[r];
    }
}

// ---------------------------------------------------------------------------
extern "C" void kernel_launch(void* const* d_in, const int* in_sizes, int n_in,
                              void* d_out, int out_size, void* d_ws, size_t ws_size,
                              hipStream_t stream)
{
    const float* x      = (const float*)d_in[0];
    const float* skip   = (const float*)d_in[1];
    const float* Wd     = (const float*)d_in[2];
    const float* gamma  = (const float*)d_in[3];
    const float* beta   = (const float*)d_in[4];
    const float* Wf     = (const float*)d_in[5];
    const int*   in_idx  = (const int*)d_in[6];
    const int*   out_idx = (const int*)d_in[7];

    float* y     = (float*)d_out;            // y lives in d_out (same shape)
    float* stats = (float*)d_ws;             // 128 floats: sum | sumsq
    float* sc    = stats + 128;              // 192 floats: s | -b/s | bias
    float4* wq   = (float4*)((float*)d_ws + 1024);   // 256 KB interleaved W

    hipMemsetAsync(d_out, 0, (size_t)N_OUT * C_OUTC * sizeof(float), stream);
    hipMemsetAsync(d_ws, 0, 128 * sizeof(float), stream);

    prep_w<<<(KK * C_IN * C_OUTC + 255) / 256, 256, 0, stream>>>(Wd, wq);

    dim3 sgrid(256, KK, 1);                  // 2048 blocks, k uniform per block
    scatter_kernel<<<sgrid, 256, 0, stream>>>(x, wq, in_idx, out_idx, y);
    stats_kernel<<<2048, 256, 0, stream>>>(y, stats);
    finalize_kernel<<<1, 64, 0, stream>>>(stats, gamma, beta, Wf, sc);
    fuse_kernel<<<1024, 512, 0, stream>>>(y, skip, Wf, sc);
}

// Round 7
// 1367.148 us; speedup vs baseline: 1.3101x; 1.3101x over previous
//
#include <hip/hip_runtime.h>

#define N_IN   100000
#define N_OUT  400000
#define KK     8
#define PP     100000
#define C_IN   128
#define C_OUTC 64
#define C_SKIP 64
#define EPS_BN 1e-5f

// ---------------------------------------------------------------------------
// Phase A: dense GEMM  z[row, kk, :] = x[row, :] @ W[k0+kk]
// Since P == N_IN per offset, computing the dense product for ALL rows does
// exactly the rulebook's FLOPs -- but with sequential (L1-hot) x reads, LDS
// weights, register accumulation, and NO atomics.
// blockIdx.y = kk (chunk-local k). Each block: 4 waves x 8 rows = 32 rows.
// ---------------------------------------------------------------------------
__global__ __launch_bounds__(256) void gemm_z(
    const float* __restrict__ x, const float* __restrict__ Wd,
    float* __restrict__ z, int k0, int kc)
{
    __shared__ float4 wlds[(C_IN / 4) * C_OUTC];   // 32 KB, wlds[iq][c]
    const int k = k0 + blockIdx.y;
    {
        const float* __restrict__ Wk = Wd + (size_t)k * (C_IN * C_OUTC);
        for (int e = threadIdx.x; e < C_IN * C_OUTC; e += 256) {
            const int i = e >> 6, c = e & 63;
            ((float*)&wlds[(i >> 2) * C_OUTC + c])[i & 3] = Wk[e];
        }
    }
    __syncthreads();

    const int lane = threadIdx.x & 63;
    const int wave = threadIdx.x >> 6;
    const int rb   = ((int)blockIdx.x * 4 + wave) * 8;    // 3125*32 = 100000
    const float4* __restrict__ x4 = (const float4*)(x + (size_t)rb * C_IN);

    float a0=0.f,a1=0.f,a2=0.f,a3=0.f,a4=0.f,a5=0.f,a6=0.f,a7=0.f;
    #pragma unroll 2
    for (int iq = 0; iq < C_IN / 4; ++iq) {
        const float4 w4 = wlds[iq * C_OUTC + lane];        // ds_read_b128
        const float4 v0 = x4[0*32 + iq]; const float4 v1 = x4[1*32 + iq];
        const float4 v2 = x4[2*32 + iq]; const float4 v3 = x4[3*32 + iq];
        const float4 v4 = x4[4*32 + iq]; const float4 v5 = x4[5*32 + iq];
        const float4 v6 = x4[6*32 + iq]; const float4 v7 = x4[7*32 + iq];
        a0 = fmaf(v0.x, w4.x, a0); a0 = fmaf(v0.y, w4.y, a0);
        a0 = fmaf(v0.z, w4.z, a0); a0 = fmaf(v0.w, w4.w, a0);
        a1 = fmaf(v1.x, w4.x, a1); a1 = fmaf(v1.y, w4.y, a1);
        a1 = fmaf(v1.z, w4.z, a1); a1 = fmaf(v1.w, w4.w, a1);
        a2 = fmaf(v2.x, w4.x, a2); a2 = fmaf(v2.y, w4.y, a2);
        a2 = fmaf(v2.z, w4.z, a2); a2 = fmaf(v2.w, w4.w, a2);
        a3 = fmaf(v3.x, w4.x, a3); a3 = fmaf(v3.y, w4.y, a3);
        a3 = fmaf(v3.z, w4.z, a3); a3 = fmaf(v3.w, w4.w, a3);
        a4 = fmaf(v4.x, w4.x, a4); a4 = fmaf(v4.y, w4.y, a4);
        a4 = fmaf(v4.z, w4.z, a4); a4 = fmaf(v4.w, w4.w, a4);
        a5 = fmaf(v5.x, w4.x, a5); a5 = fmaf(v5.y, w4.y, a5);
        a5 = fmaf(v5.z, w4.z, a5); a5 = fmaf(v5.w, w4.w, a5);
        a6 = fmaf(v6.x, w4.x, a6); a6 = fmaf(v6.y, w4.y, a6);
        a6 = fmaf(v6.z, w4.z, a6); a6 = fmaf(v6.w, w4.w, a6);
        a7 = fmaf(v7.x, w4.x, a7); a7 = fmaf(v7.y, w4.y, a7);
        a7 = fmaf(v7.z, w4.z, a7); a7 = fmaf(v7.w, w4.w, a7);
    }

    const size_t zs = (size_t)kc * C_OUTC;                 // row stride in z
    float* __restrict__ zr = z + (size_t)rb * zs + (size_t)blockIdx.y * C_OUTC + lane;
    zr[0*zs]=a0; zr[1*zs]=a1; zr[2*zs]=a2; zr[3*zs]=a3;
    zr[4*zs]=a4; zr[5*zs]=a5; zr[6*zs]=a6; zr[7*zs]=a7;
}

// ---------------------------------------------------------------------------
// Phase B: pure scatter:  y[out_idx[q]] += z[in_idx[q], k-k0]
// One coalesced 256 B z-row read + 64 dword atomics per pair; no compute to
// stall, tiny VGPR -> full occupancy; bounded by atomic throughput only.
// Covers pairs q in [k0*PP, (k0+kc)*PP), 4 pairs per wave-iteration.
// ---------------------------------------------------------------------------
__global__ __launch_bounds__(256) void scatter_add(
    const float* __restrict__ z, const int* __restrict__ in_idx,
    const int* __restrict__ out_idx, float* __restrict__ y, int k0, int kc)
{
    const int lane = threadIdx.x & 63;
    const int wv   = (int)((blockIdx.x * 256 + threadIdx.x) >> 6);
    const int nw   = (int)gridDim.x * 4;
    const int4* __restrict__ in4  = (const int4*)in_idx;
    const int4* __restrict__ out4 = (const int4*)out_idx;
    const size_t zs = (size_t)kc * C_OUTC;
    const int g0 = k0 * (PP / 4), g1 = (k0 + kc) * (PP / 4);

    for (int g = g0 + wv; g < g1; g += nw) {
        const int4 i4 = in4[g];
        const int4 o4 = out4[g];
        const int kk = g / (PP / 4) - k0;                  // uniform (PP%4==0)
        const size_t kb = (size_t)kk * C_OUTC + lane;
        const float v0 = z[(size_t)i4.x * zs + kb];
        const float v1 = z[(size_t)i4.y * zs + kb];
        const float v2 = z[(size_t)i4.z * zs + kb];
        const float v3 = z[(size_t)i4.w * zs + kb];
        atomicAdd(&y[(size_t)o4.x * C_OUTC + lane], v0);
        atomicAdd(&y[(size_t)o4.y * C_OUTC + lane], v1);
        atomicAdd(&y[(size_t)o4.z * C_OUTC + lane], v2);
        atomicAdd(&y[(size_t)o4.w * C_OUTC + lane], v3);
    }
}

// ---------------------------------------------------------------------------
// Per-channel sum / sumsq over y (float4 per thread) -> stats[0:64] | [64:128]
// ---------------------------------------------------------------------------
__global__ __launch_bounds__(256) void stats_kernel(
    const float* __restrict__ y, float* __restrict__ stats)
{
    const int tid = threadIdx.x;
    const int cq  = tid & 15;                          // channel quad 0..15
    const int rid = (int)((blockIdx.x * 256 + tid) >> 4);
    const int nr  = (int)(gridDim.x * 256) >> 4;
    const float4* __restrict__ y4 = (const float4*)y;

    float sx=0,sy=0,sz=0,sw=0, qx=0,qy=0,qz=0,qw=0;
    for (int r = rid; r < N_OUT; r += nr) {
        const float4 v = y4[(size_t)r * 16 + cq];
        sx += v.x; sy += v.y; sz += v.z; sw += v.w;
        qx = fmaf(v.x, v.x, qx); qy = fmaf(v.y, v.y, qy);
        qz = fmaf(v.z, v.z, qz); qw = fmaf(v.w, v.w, qw);
    }
    __shared__ float ls[4 * 256];
    __shared__ float lq[4 * 256];
    ls[0*256+tid]=sx; ls[1*256+tid]=sy; ls[2*256+tid]=sz; ls[3*256+tid]=sw;
    lq[0*256+tid]=qx; lq[1*256+tid]=qy; lq[2*256+tid]=qz; lq[3*256+tid]=qw;
    __syncthreads();
    for (int off = 128; off >= 16; off >>= 1) {
        if (tid < off) {
            #pragma unroll
            for (int c = 0; c < 4; ++c) {
                ls[c*256+tid] += ls[c*256+tid+off];
                lq[c*256+tid] += lq[c*256+tid+off];
            }
        }
        __syncthreads();
    }
    if (tid < 16) {
        #pragma unroll
        for (int c = 0; c < 4; ++c) {
            atomicAdd(&stats[tid * 4 + c],           ls[c*256+tid]);
            atomicAdd(&stats[C_OUTC + tid * 4 + c],  lq[c*256+tid]);
        }
    }
}

// ---------------------------------------------------------------------------
// Fold BN into fuse-friendly constants.
//  s[i]   = gamma*rsqrt(var+eps)          (sc[0:64])
//  nb[i]  = -(beta - mean*s)/s            (sc[64:128])
//  bias[c]= sum_i b_i * Wf[i][c]          (sc[128:192])
// relu(y*s+b) @ W = max(y, -b/s) @ (diag(s)W) + (b @ W), s > 0.
// ---------------------------------------------------------------------------
__global__ void finalize_kernel(const float* __restrict__ stats,
                                const float* __restrict__ gamma,
                                const float* __restrict__ beta,
                                const float* __restrict__ Wf,
                                float* __restrict__ sc)
{
    __shared__ float bsh[C_OUTC];
    const int c = threadIdx.x;                 // 64 threads
    const float inv_n = 1.0f / (float)N_OUT;
    const float mean  = stats[c] * inv_n;
    const float var   = stats[C_OUTC + c] * inv_n - mean * mean;
    const float s     = gamma[c] * rsqrtf(var + EPS_BN);
    const float b     = beta[c] - mean * s;
    sc[c]            = s;
    sc[C_OUTC + c]   = -b / s;
    bsh[c] = b;
    __syncthreads();
    float acc = 0.f;
    for (int i = 0; i < C_OUTC; ++i)
        acc = fmaf(bsh[i], Wf[i * C_OUTC + c], acc);
    sc[2 * C_OUTC + c] = acc;
}

// ---------------------------------------------------------------------------
// Fused BN+ReLU+concat+linear, in-place on y (unchanged; isolates this round's
// deconv change -- fuse is the next target once profiled).
// ---------------------------------------------------------------------------
__global__ __launch_bounds__(512) void fuse_kernel(
    float* __restrict__ y, const float* __restrict__ skip,
    const float* __restrict__ Wf, const float* __restrict__ sc)
{
    __shared__ float wlds[C_IN * C_OUTC];          // [i][c], y-half pre-scaled
    __shared__ float nb[C_OUTC];
    for (int e = threadIdx.x; e < C_IN * C_OUTC; e += 512) {
        const int i = e >> 6;
        const float w = Wf[e];
        wlds[e] = (i < C_OUTC) ? w * sc[i] : w;
    }
    if (threadIdx.x < C_OUTC) nb[threadIdx.x] = sc[C_OUTC + threadIdx.x];
    __syncthreads();

    const int lane = threadIdx.x & 63;
    int wv = (int)((blockIdx.x * 512 + threadIdx.x) >> 6);
    wv = __builtin_amdgcn_readfirstlane(wv);       // SGPR wave id -> s_load rows
    const int nw = (int)gridDim.x * 8;
    const float bias0 = sc[2 * C_OUTC + lane];

    for (int g = wv; g < N_OUT / 8; g += nw) {
        const float* __restrict__ yr = y    + (size_t)g * 8 * C_OUTC;
        const float* __restrict__ sr = skip + (size_t)g * 8 * C_SKIP;

        float acc[8];
        #pragma unroll
        for (int r = 0; r < 8; ++r) acc[r] = bias0;

        #pragma unroll 8
        for (int i = 0; i < C_OUTC; ++i) {
            const float w = wlds[i * C_OUTC + lane];
            const float t = nb[i];
            #pragma unroll
            for (int r = 0; r < 8; ++r)
                acc[r] = fmaf(fmaxf(yr[r * C_OUTC + i], t), w, acc[r]);
        }
        #pragma unroll 8
        for (int i = 0; i < C_SKIP; ++i) {
            const float w = wlds[(C_OUTC + i) * C_OUTC + lane];
            #pragma unroll
            for (int r = 0; r < 8; ++r)
                acc[r] = fmaf(sr[r * C_SKIP + i], w, acc[r]);
        }
        #pragma unroll
        for (int r = 0; r < 8; ++r)
            y[((size_t)g * 8 + r) * C_OUTC + lane] = acc[r];
    }
}

// ---------------------------------------------------------------------------
extern "C" void kernel_launch(void* const* d_in, const int* in_sizes, int n_in,
                              void* d_out, int out_size, void* d_ws, size_t ws_size,
                              hipStream_t stream)
{
    const float* x      = (const float*)d_in[0];
    const float* skip   = (const float*)d_in[1];
    const float* Wd     = (const float*)d_in[2];
    const float* gamma  = (const float*)d_in[3];
    const float* beta   = (const float*)d_in[4];
    const float* Wf     = (const float*)d_in[5];
    const int*   in_idx  = (const int*)d_in[6];
    const int*   out_idx = (const int*)d_in[7];

    float* y     = (float*)d_out;            // y lives in d_out (same shape)
    float* stats = (float*)d_ws;             // 128 floats: sum | sumsq
    float* sc    = stats + 128;              // 192 floats: s | -b/s | bias
    float* z     = (float*)((char*)d_ws + 4096);   // k-chunked z buffer

    // How many k-offsets fit in the workspace at once (25.6 MB per k)?
    const size_t zbytes_per_k = (size_t)N_IN * C_OUTC * sizeof(float);
    size_t avail = (ws_size > 4096) ? (ws_size - 4096) : 0;
    int kc = (int)(avail / zbytes_per_k);
    if (kc > KK) kc = KK;
    if (kc < 1)  kc = 1;                     // (ws too small would be fatal anyway)

    hipMemsetAsync(d_out, 0, (size_t)N_OUT * C_OUTC * sizeof(float), stream);
    hipMemsetAsync(d_ws, 0, 128 * sizeof(float), stream);

    for (int k0 = 0; k0 < KK; k0 += kc) {
        const int c = (k0 + kc <= KK) ? kc : (KK - k0);
        dim3 ggrid(N_IN / 32, c, 1);         // 3125 x c blocks
        gemm_z<<<ggrid, 256, 0, stream>>>(x, Wd, z, k0, c);
        scatter_add<<<2048, 256, 0, stream>>>(z, in_idx, out_idx, y, k0, c);
    }

    stats_kernel<<<2048, 256, 0, stream>>>(y, stats);
    finalize_kernel<<<1, 64, 0, stream>>>(stats, gamma, beta, Wf, sc);
    fuse_kernel<<<1024, 512, 0, stream>>>(y, skip, Wf, sc);
}

// Round 8
// 695.113 us; speedup vs baseline: 2.5766x; 1.9668x over previous
//
#include <hip/hip_runtime.h>

#define N_IN   100000
#define N_OUT  400000
#define KK     8
#define PP     100000
#define C_IN   128
#define C_OUTC 64
#define C_SKIP 64
#define EPS_BN 1e-5f

typedef __attribute__((ext_vector_type(8))) short bf16x8;
typedef __attribute__((ext_vector_type(4))) float f32x4;

// round-to-nearest-even f32 -> bf16 (inputs are finite randoms; no NaN care)
__device__ __forceinline__ unsigned short f2b(float f) {
    unsigned int u = __builtin_bit_cast(unsigned int, f);
    return (unsigned short)((u + 0x7FFFu + ((u >> 16) & 1u)) >> 16);
}

// ---------------------------------------------------------------------------
// x (f32) -> xb (bf16), 8 elems/thread, fully coalesced.
// ---------------------------------------------------------------------------
__global__ __launch_bounds__(256) void xcast(
    const float4* __restrict__ x, unsigned short* __restrict__ xb)
{
    const int t = blockIdx.x * 256 + threadIdx.x;      // over N_IN*C_IN/8
    if (t < N_IN * C_IN / 8) {
        const float4 v0 = x[2 * t], v1 = x[2 * t + 1];
        uint4 o;
        o.x = f2b(v0.x) | ((unsigned)f2b(v0.y) << 16);
        o.y = f2b(v0.z) | ((unsigned)f2b(v0.w) << 16);
        o.z = f2b(v1.x) | ((unsigned)f2b(v1.y) << 16);
        o.w = f2b(v1.z) | ((unsigned)f2b(v1.w) << 16);
        ((uint4*)xb)[t] = o;
    }
}

// ---------------------------------------------------------------------------
// W (f32 [k][i][c]) -> bfrag (bf16), pre-swizzled into the MFMA B-fragment
// lane layout: bfrag[((ko*4+ks)*4+ct)*512 + l*8 + j] = W[ko][ks*32+(l>>4)*8+j][ct*16+(l&15)]
// so the GEMM's B load is one coalesced 16B/lane dwordx4. 128 KB total.
// ---------------------------------------------------------------------------
__global__ __launch_bounds__(256) void prep_bfrag(
    const float* __restrict__ Wd, unsigned short* __restrict__ bfrag)
{
    const int e = blockIdx.x * 256 + threadIdx.x;      // 65536
    if (e < KK * 4 * 4 * 64 * 8) {
        const int j  = e & 7;
        const int l  = (e >> 3) & 63;
        const int ct = (e >> 9) & 3;
        const int ks = (e >> 11) & 3;
        const int ko = e >> 13;
        const int i  = ks * 32 + (l >> 4) * 8 + j;
        const int c  = ct * 16 + (l & 15);
        bfrag[e] = f2b(Wd[((size_t)ko * C_IN + i) * C_OUTC + c]);
    }
}

// ---------------------------------------------------------------------------
// Phase A: z[row, kol, :] = x[row, :] @ W[k0+kol]  via mfma_f32_16x16x32_bf16.
// Block = 32 rows x 4 waves; wave kol = blockIdx.y*4 + wv (one k-offset).
// A tile (32x128 bf16) staged in LDS with 272B-padded rows (bank-balanced
// ds_read_b128). 32 MFMA/wave. z-write-bound (~205 MB).
// C layout per m89: row = (l>>4)*4 + j, col = l&15.
// ---------------------------------------------------------------------------
__global__ __launch_bounds__(256) void gemm_mfma(
    const unsigned short* __restrict__ xb, const unsigned short* __restrict__ bfrag,
    float* __restrict__ z, int k0, int kc)
{
    __shared__ __align__(16) unsigned short alds[32 * 136];   // 272B row stride
    const int rb = blockIdx.x * 32;
    for (int cch = threadIdx.x; cch < 32 * 16; cch += 256) {
        const int row = cch >> 4, ch = cch & 15;
        *(uint4*)(&alds[row * 136 + ch * 8]) =
            *(const uint4*)(xb + (size_t)(rb + row) * C_IN + ch * 8);
    }
    __syncthreads();

    const int kol = (int)blockIdx.y * 4 + (threadIdx.x >> 6);
    if (kol >= kc) return;                      // no barriers after this point
    const int ko  = k0 + kol;
    const int l   = threadIdx.x & 63;
    const int r16 = l & 15, hi = l >> 4;

    f32x4 acc[2][4];
    #pragma unroll
    for (int rt = 0; rt < 2; ++rt)
        #pragma unroll
        for (int ct = 0; ct < 4; ++ct)
            acc[rt][ct] = (f32x4){0.f, 0.f, 0.f, 0.f};

    const unsigned short* __restrict__ bk = bfrag + (size_t)ko * 8192;
    #pragma unroll
    for (int ks = 0; ks < 4; ++ks) {
        const bf16x8 a0 = *(const bf16x8*)(&alds[r16 * 136 + ks * 32 + hi * 8]);
        const bf16x8 a1 = *(const bf16x8*)(&alds[(16 + r16) * 136 + ks * 32 + hi * 8]);
        #pragma unroll
        for (int ct = 0; ct < 4; ++ct) {
            const bf16x8 b = *(const bf16x8*)(bk + ((ks * 4 + ct) * 64 + l) * 8);
            acc[0][ct] = __builtin_amdgcn_mfma_f32_16x16x32_bf16(a0, b, acc[0][ct], 0, 0, 0);
            acc[1][ct] = __builtin_amdgcn_mfma_f32_16x16x32_bf16(a1, b, acc[1][ct], 0, 0, 0);
        }
    }

    const size_t zs = (size_t)kc * C_OUTC;
    #pragma unroll
    for (int rt = 0; rt < 2; ++rt)
        #pragma unroll
        for (int ct = 0; ct < 4; ++ct)
            #pragma unroll
            for (int j = 0; j < 4; ++j)
                z[(size_t)(rb + rt * 16 + hi * 4 + j) * zs + kol * 64 + ct * 16 + r16]
                    = acc[rt][ct][j];
}

// ---------------------------------------------------------------------------
// Phase B: pure scatter:  y[out_idx[q]] += z[in_idx[q], k-k0]   (unchanged)
// ---------------------------------------------------------------------------
__global__ __launch_bounds__(256) void scatter_add(
    const float* __restrict__ z, const int* __restrict__ in_idx,
    const int* __restrict__ out_idx, float* __restrict__ y, int k0, int kc)
{
    const int lane = threadIdx.x & 63;
    const int wv   = (int)((blockIdx.x * 256 + threadIdx.x) >> 6);
    const int nw   = (int)gridDim.x * 4;
    const int4* __restrict__ in4  = (const int4*)in_idx;
    const int4* __restrict__ out4 = (const int4*)out_idx;
    const size_t zs = (size_t)kc * C_OUTC;
    const int g0 = k0 * (PP / 4), g1 = (k0 + kc) * (PP / 4);

    for (int g = g0 + wv; g < g1; g += nw) {
        const int4 i4 = in4[g];
        const int4 o4 = out4[g];
        const int kk = g / (PP / 4) - k0;                  // uniform (PP%4==0)
        const size_t kb = (size_t)kk * C_OUTC + lane;
        const float v0 = z[(size_t)i4.x * zs + kb];
        const float v1 = z[(size_t)i4.y * zs + kb];
        const float v2 = z[(size_t)i4.z * zs + kb];
        const float v3 = z[(size_t)i4.w * zs + kb];
        atomicAdd(&y[(size_t)o4.x * C_OUTC + lane], v0);
        atomicAdd(&y[(size_t)o4.y * C_OUTC + lane], v1);
        atomicAdd(&y[(size_t)o4.z * C_OUTC + lane], v2);
        atomicAdd(&y[(size_t)o4.w * C_OUTC + lane], v3);
    }
}

// ---------------------------------------------------------------------------
// Per-channel sum / sumsq over y (float4 per thread) -> stats[0:64] | [64:128]
// ---------------------------------------------------------------------------
__global__ __launch_bounds__(256) void stats_kernel(
    const float* __restrict__ y, float* __restrict__ stats)
{
    const int tid = threadIdx.x;
    const int cq  = tid & 15;                          // channel quad 0..15
    const int rid = (int)((blockIdx.x * 256 + tid) >> 4);
    const int nr  = (int)(gridDim.x * 256) >> 4;
    const float4* __restrict__ y4 = (const float4*)y;

    float sx=0,sy=0,sz=0,sw=0, qx=0,qy=0,qz=0,qw=0;
    for (int r = rid; r < N_OUT; r += nr) {
        const float4 v = y4[(size_t)r * 16 + cq];
        sx += v.x; sy += v.y; sz += v.z; sw += v.w;
        qx = fmaf(v.x, v.x, qx); qy = fmaf(v.y, v.y, qy);
        qz = fmaf(v.z, v.z, qz); qw = fmaf(v.w, v.w, qw);
    }
    __shared__ float ls[4 * 256];
    __shared__ float lq[4 * 256];
    ls[0*256+tid]=sx; ls[1*256+tid]=sy; ls[2*256+tid]=sz; ls[3*256+tid]=sw;
    lq[0*256+tid]=qx; lq[1*256+tid]=qy; lq[2*256+tid]=qz; lq[3*256+tid]=qw;
    __syncthreads();
    for (int off = 128; off >= 16; off >>= 1) {
        if (tid < off) {
            #pragma unroll
            for (int c = 0; c < 4; ++c) {
                ls[c*256+tid] += ls[c*256+tid+off];
                lq[c*256+tid] += lq[c*256+tid+off];
            }
        }
        __syncthreads();
    }
    if (tid < 16) {
        #pragma unroll
        for (int c = 0; c < 4; ++c) {
            atomicAdd(&stats[tid * 4 + c],           ls[c*256+tid]);
            atomicAdd(&stats[C_OUTC + tid * 4 + c],  lq[c*256+tid]);
        }
    }
}

// ---------------------------------------------------------------------------
// Fold BN into fuse-friendly constants.
//  s[i]   = gamma*rsqrt(var+eps)          (sc[0:64])
//  nb[i]  = -(beta - mean*s)/s            (sc[64:128])
//  bias[c]= sum_i b_i * Wf[i][c]          (sc[128:192])
// relu(y*s+b) @ W = max(y, -b/s) @ (diag(s)W) + (b @ W), s > 0.
// ---------------------------------------------------------------------------
__global__ void finalize_kernel(const float* __restrict__ stats,
                                const float* __restrict__ gamma,
                                const float* __restrict__ beta,
                                const float* __restrict__ Wf,
                                float* __restrict__ sc)
{
    __shared__ float bsh[C_OUTC];
    const int c = threadIdx.x;                 // 64 threads
    const float inv_n = 1.0f / (float)N_OUT;
    const float mean  = stats[c] * inv_n;
    const float var   = stats[C_OUTC + c] * inv_n - mean * mean;
    const float s     = gamma[c] * rsqrtf(var + EPS_BN);
    const float b     = beta[c] - mean * s;
    sc[c]            = s;
    sc[C_OUTC + c]   = -b / s;
    bsh[c] = b;
    __syncthreads();
    float acc = 0.f;
    for (int i = 0; i < C_OUTC; ++i)
        acc = fmaf(bsh[i], Wf[i * C_OUTC + c], acc);
    sc[2 * C_OUTC + c] = acc;
}

// ---------------------------------------------------------------------------
// Fused BN+ReLU+concat+linear, in-place on y (unchanged this round).
// ---------------------------------------------------------------------------
__global__ __launch_bounds__(512) void fuse_kernel(
    float* __restrict__ y, const float* __restrict__ skip,
    const float* __restrict__ Wf, const float* __restrict__ sc)
{
    __shared__ float wlds[C_IN * C_OUTC];          // [i][c], y-half pre-scaled
    __shared__ float nb[C_OUTC];
    for (int e = threadIdx.x; e < C_IN * C_OUTC; e += 512) {
        const int i = e >> 6;
        const float w = Wf[e];
        wlds[e] = (i < C_OUTC) ? w * sc[i] : w;
    }
    if (threadIdx.x < C_OUTC) nb[threadIdx.x] = sc[C_OUTC + threadIdx.x];
    __syncthreads();

    const int lane = threadIdx.x & 63;
    int wv = (int)((blockIdx.x * 512 + threadIdx.x) >> 6);
    wv = __builtin_amdgcn_readfirstlane(wv);       // SGPR wave id -> s_load rows
    const int nw = (int)gridDim.x * 8;
    const float bias0 = sc[2 * C_OUTC + lane];

    for (int g = wv; g < N_OUT / 8; g += nw) {
        const float* __restrict__ yr = y    + (size_t)g * 8 * C_OUTC;
        const float* __restrict__ sr = skip + (size_t)g * 8 * C_SKIP;

        float acc[8];
        #pragma unroll
        for (int r = 0; r < 8; ++r) acc[r] = bias0;

        #pragma unroll 8
        for (int i = 0; i < C_OUTC; ++i) {
            const float w = wlds[i * C_OUTC + lane];
            const float t = nb[i];
            #pragma unroll
            for (int r = 0; r < 8; ++r)
                acc[r] = fmaf(fmaxf(yr[r * C_OUTC + i], t), w, acc[r]);
        }
        #pragma unroll 8
        for (int i = 0; i < C_SKIP; ++i) {
            const float w = wlds[(C_OUTC + i) * C_OUTC + lane];
            #pragma unroll
            for (int r = 0; r < 8; ++r)
                acc[r] = fmaf(sr[r * C_SKIP + i], w, acc[r]);
        }
        #pragma unroll
        for (int r = 0; r < 8; ++r)
            y[((size_t)g * 8 + r) * C_OUTC + lane] = acc[r];
    }
}

// ---------------------------------------------------------------------------
extern "C" void kernel_launch(void* const* d_in, const int* in_sizes, int n_in,
                              void* d_out, int out_size, void* d_ws, size_t ws_size,
                              hipStream_t stream)
{
    const float* x      = (const float*)d_in[0];
    const float* skip   = (const float*)d_in[1];
    const float* Wd     = (const float*)d_in[2];
    const float* gamma  = (const float*)d_in[3];
    const float* beta   = (const float*)d_in[4];
    const float* Wf     = (const float*)d_in[5];
    const int*   in_idx  = (const int*)d_in[6];
    const int*   out_idx = (const int*)d_in[7];

    float* y     = (float*)d_out;            // y lives in d_out (same shape)
    float* stats = (float*)d_ws;             // 128 floats: sum | sumsq
    float* sc    = stats + 128;              // 192 floats: s | -b/s | bias

    unsigned short* xb    = (unsigned short*)((char*)d_ws + 4096);   // 25.6 MB
    unsigned short* bfrag = xb + (size_t)N_IN * C_IN;                // 128 KB
    const size_t zoff = 4096 + (size_t)N_IN * C_IN * 2 + KK * 8192 * 2;
    float* z = (float*)((char*)d_ws + zoff);

    const size_t zbytes_per_k = (size_t)N_IN * C_OUTC * sizeof(float);
    int kc = (ws_size > zoff) ? (int)((ws_size - zoff) / zbytes_per_k) : 1;
    if (kc > KK) kc = KK;
    if (kc < 1)  kc = 1;

    hipMemsetAsync(d_out, 0, (size_t)N_OUT * C_OUTC * sizeof(float), stream);
    hipMemsetAsync(d_ws, 0, 128 * sizeof(float), stream);

    xcast<<<(N_IN * C_IN / 8 + 255) / 256, 256, 0, stream>>>((const float4*)x, xb);
    prep_bfrag<<<(KK * 8192 + 255) / 256, 256, 0, stream>>>(Wd, bfrag);

    for (int k0 = 0; k0 < KK; k0 += kc) {
        const int c = (k0 + kc <= KK) ? kc : (KK - k0);
        dim3 ggrid(N_IN / 32, (c + 3) / 4, 1);
        gemm_mfma<<<ggrid, 256, 0, stream>>>(xb, bfrag, z, k0, c);
        scatter_add<<<2048, 256, 0, stream>>>(z, in_idx, out_idx, y, k0, c);
    }

    stats_kernel<<<2048, 256, 0, stream>>>(y, stats);
    finalize_kernel<<<1, 64, 0, stream>>>(stats, gamma, beta, Wf, sc);
    fuse_kernel<<<1024, 512, 0, stream>>>(y, skip, Wf, sc);
}

// Round 9
// 546.656 us; speedup vs baseline: 3.2764x; 1.2716x over previous
//
#include <hip/hip_runtime.h>

#define N_IN   100000
#define N_OUT  400000
#define KK     8
#define PP     100000
#define C_IN   128
#define C_OUTC 64
#define C_SKIP 64
#define EPS_BN 1e-5f

typedef __attribute__((ext_vector_type(8))) short bf16x8;
typedef __attribute__((ext_vector_type(4))) float f32x4;

// round-to-nearest-even f32 -> bf16 (inputs are finite randoms; no NaN care)
__device__ __forceinline__ unsigned short f2b(float f) {
    unsigned int u = __builtin_bit_cast(unsigned int, f);
    return (unsigned short)((u + 0x7FFFu + ((u >> 16) & 1u)) >> 16);
}

// ---------------------------------------------------------------------------
// x (f32) -> xb (bf16), 8 elems/thread, fully coalesced.
// ---------------------------------------------------------------------------
__global__ __launch_bounds__(256) void xcast(
    const float4* __restrict__ x, unsigned short* __restrict__ xb)
{
    const int t = blockIdx.x * 256 + threadIdx.x;      // over N_IN*C_IN/8
    if (t < N_IN * C_IN / 8) {
        const float4 v0 = x[2 * t], v1 = x[2 * t + 1];
        uint4 o;
        o.x = f2b(v0.x) | ((unsigned)f2b(v0.y) << 16);
        o.y = f2b(v0.z) | ((unsigned)f2b(v0.w) << 16);
        o.z = f2b(v1.x) | ((unsigned)f2b(v1.y) << 16);
        o.w = f2b(v1.z) | ((unsigned)f2b(v1.w) << 16);
        ((uint4*)xb)[t] = o;
    }
}

// ---------------------------------------------------------------------------
// W (f32 [k][i][c]) -> bfrag (bf16), pre-swizzled into the MFMA B-fragment
// lane layout: bfrag[((ko*4+ks)*4+ct)*512 + l*8 + j] = W[ko][ks*32+(l>>4)*8+j][ct*16+(l&15)]
// so the GEMM's B load is one coalesced 16B/lane dwordx4. 128 KB total.
// ---------------------------------------------------------------------------
__global__ __launch_bounds__(256) void prep_bfrag(
    const float* __restrict__ Wd, unsigned short* __restrict__ bfrag)
{
    const int e = blockIdx.x * 256 + threadIdx.x;      // 65536
    if (e < KK * 4 * 4 * 64 * 8) {
        const int j  = e & 7;
        const int l  = (e >> 3) & 63;
        const int ct = (e >> 9) & 3;
        const int ks = (e >> 11) & 3;
        const int ko = e >> 13;
        const int i  = ks * 32 + (l >> 4) * 8 + j;
        const int c  = ct * 16 + (l & 15);
        bfrag[e] = f2b(Wd[((size_t)ko * C_IN + i) * C_OUTC + c]);
    }
}

// ---------------------------------------------------------------------------
// Phase A: z[row, kol, :] = x[row, :] @ W[k0+kol]  via mfma_f32_16x16x32_bf16.
// Block = 32 rows x 4 waves; wave kol = blockIdx.y*4 + wv (one k-offset).
// A tile (32x128 bf16) staged in LDS with 272B-padded rows (2-way = free).
// C layout per m89: row = (l>>4)*4 + j, col = l&15.
// ---------------------------------------------------------------------------
__global__ __launch_bounds__(256) void gemm_mfma(
    const unsigned short* __restrict__ xb, const unsigned short* __restrict__ bfrag,
    float* __restrict__ z, int k0, int kc)
{
    __shared__ __align__(16) unsigned short alds[32 * 136];   // 272B row stride
    const int rb = blockIdx.x * 32;
    for (int cch = threadIdx.x; cch < 32 * 16; cch += 256) {
        const int row = cch >> 4, ch = cch & 15;
        *(uint4*)(&alds[row * 136 + ch * 8]) =
            *(const uint4*)(xb + (size_t)(rb + row) * C_IN + ch * 8);
    }
    __syncthreads();

    const int kol = (int)blockIdx.y * 4 + (threadIdx.x >> 6);
    if (kol >= kc) return;                      // no barriers after this point
    const int ko  = k0 + kol;
    const int l   = threadIdx.x & 63;
    const int r16 = l & 15, hi = l >> 4;

    f32x4 acc[2][4];
    #pragma unroll
    for (int rt = 0; rt < 2; ++rt)
        #pragma unroll
        for (int ct = 0; ct < 4; ++ct)
            acc[rt][ct] = (f32x4){0.f, 0.f, 0.f, 0.f};

    const unsigned short* __restrict__ bk = bfrag + (size_t)ko * 8192;
    #pragma unroll
    for (int ks = 0; ks < 4; ++ks) {
        const bf16x8 a0 = *(const bf16x8*)(&alds[r16 * 136 + ks * 32 + hi * 8]);
        const bf16x8 a1 = *(const bf16x8*)(&alds[(16 + r16) * 136 + ks * 32 + hi * 8]);
        #pragma unroll
        for (int ct = 0; ct < 4; ++ct) {
            const bf16x8 b = *(const bf16x8*)(bk + ((ks * 4 + ct) * 64 + l) * 8);
            acc[0][ct] = __builtin_amdgcn_mfma_f32_16x16x32_bf16(a0, b, acc[0][ct], 0, 0, 0);
            acc[1][ct] = __builtin_amdgcn_mfma_f32_16x16x32_bf16(a1, b, acc[1][ct], 0, 0, 0);
        }
    }

    const size_t zs = (size_t)kc * C_OUTC;
    #pragma unroll
    for (int rt = 0; rt < 2; ++rt)
        #pragma unroll
        for (int ct = 0; ct < 4; ++ct)
            #pragma unroll
            for (int j = 0; j < 4; ++j)
                z[(size_t)(rb + rt * 16 + hi * 4 + j) * zs + kol * 64 + ct * 16 + r16]
                    = acc[rt][ct][j];
}

// ---------------------------------------------------------------------------
// Phase B: pure scatter:  y[out_idx[q]] += z[in_idx[q], k-k0]   (unchanged)
// ---------------------------------------------------------------------------
__global__ __launch_bounds__(256) void scatter_add(
    const float* __restrict__ z, const int* __restrict__ in_idx,
    const int* __restrict__ out_idx, float* __restrict__ y, int k0, int kc)
{
    const int lane = threadIdx.x & 63;
    const int wv   = (int)((blockIdx.x * 256 + threadIdx.x) >> 6);
    const int nw   = (int)gridDim.x * 4;
    const int4* __restrict__ in4  = (const int4*)in_idx;
    const int4* __restrict__ out4 = (const int4*)out_idx;
    const size_t zs = (size_t)kc * C_OUTC;
    const int g0 = k0 * (PP / 4), g1 = (k0 + kc) * (PP / 4);

    for (int g = g0 + wv; g < g1; g += nw) {
        const int4 i4 = in4[g];
        const int4 o4 = out4[g];
        const int kk = g / (PP / 4) - k0;                  // uniform (PP%4==0)
        const size_t kb = (size_t)kk * C_OUTC + lane;
        const float v0 = z[(size_t)i4.x * zs + kb];
        const float v1 = z[(size_t)i4.y * zs + kb];
        const float v2 = z[(size_t)i4.z * zs + kb];
        const float v3 = z[(size_t)i4.w * zs + kb];
        atomicAdd(&y[(size_t)o4.x * C_OUTC + lane], v0);
        atomicAdd(&y[(size_t)o4.y * C_OUTC + lane], v1);
        atomicAdd(&y[(size_t)o4.z * C_OUTC + lane], v2);
        atomicAdd(&y[(size_t)o4.w * C_OUTC + lane], v3);
    }
}

// ---------------------------------------------------------------------------
// Per-channel sum / sumsq over y (float4 per thread) -> stats[0:64] | [64:128]
// ---------------------------------------------------------------------------
__global__ __launch_bounds__(256) void stats_kernel(
    const float* __restrict__ y, float* __restrict__ stats)
{
    const int tid = threadIdx.x;
    const int cq  = tid & 15;                          // channel quad 0..15
    const int rid = (int)((blockIdx.x * 256 + tid) >> 4);
    const int nr  = (int)(gridDim.x * 256) >> 4;
    const float4* __restrict__ y4 = (const float4*)y;

    float sx=0,sy=0,sz=0,sw=0, qx=0,qy=0,qz=0,qw=0;
    for (int r = rid; r < N_OUT; r += nr) {
        const float4 v = y4[(size_t)r * 16 + cq];
        sx += v.x; sy += v.y; sz += v.z; sw += v.w;
        qx = fmaf(v.x, v.x, qx); qy = fmaf(v.y, v.y, qy);
        qz = fmaf(v.z, v.z, qz); qw = fmaf(v.w, v.w, qw);
    }
    __shared__ float ls[4 * 256];
    __shared__ float lq[4 * 256];
    ls[0*256+tid]=sx; ls[1*256+tid]=sy; ls[2*256+tid]=sz; ls[3*256+tid]=sw;
    lq[0*256+tid]=qx; lq[1*256+tid]=qy; lq[2*256+tid]=qz; lq[3*256+tid]=qw;
    __syncthreads();
    for (int off = 128; off >= 16; off >>= 1) {
        if (tid < off) {
            #pragma unroll
            for (int c = 0; c < 4; ++c) {
                ls[c*256+tid] += ls[c*256+tid+off];
                lq[c*256+tid] += lq[c*256+tid+off];
            }
        }
        __syncthreads();
    }
    if (tid < 16) {
        #pragma unroll
        for (int c = 0; c < 4; ++c) {
            atomicAdd(&stats[tid * 4 + c],           ls[c*256+tid]);
            atomicAdd(&stats[C_OUTC + tid * 4 + c],  lq[c*256+tid]);
        }
    }
}

// ---------------------------------------------------------------------------
// Fold BN into fuse-friendly constants.
//  s[i]   = gamma*rsqrt(var+eps)          (sc[0:64])
//  nb[i]  = -(beta - mean*s)/s            (sc[64:128])
//  bias[c]= sum_i b_i * Wf[i][c]          (sc[128:192])
// relu(y*s+b) @ W = max(y, -b/s) @ (diag(s)W) + (b @ W), s > 0.
// ---------------------------------------------------------------------------
__global__ void finalize_kernel(const float* __restrict__ stats,
                                const float* __restrict__ gamma,
                                const float* __restrict__ beta,
                                const float* __restrict__ Wf,
                                float* __restrict__ sc)
{
    __shared__ float bsh[C_OUTC];
    const int c = threadIdx.x;                 // 64 threads
    const float inv_n = 1.0f / (float)N_OUT;
    const float mean  = stats[c] * inv_n;
    const float var   = stats[C_OUTC + c] * inv_n - mean * mean;
    const float s     = gamma[c] * rsqrtf(var + EPS_BN);
    const float b     = beta[c] - mean * s;
    sc[c]            = s;
    sc[C_OUTC + c]   = -b / s;
    bsh[c] = b;
    __syncthreads();
    float acc = 0.f;
    for (int i = 0; i < C_OUTC; ++i)
        acc = fmaf(bsh[i], Wf[i * C_OUTC + c], acc);
    sc[2 * C_OUTC + c] = acc;
}

// ---------------------------------------------------------------------------
// Wf (f32, BN-scale folded into rows 0..63) -> bf16 B-fragment layout
// (same swizzle as prep_bfrag). 16 KB; runs after finalize_kernel.
// ---------------------------------------------------------------------------
__global__ __launch_bounds__(256) void prep_ffrag(
    const float* __restrict__ Wf, const float* __restrict__ sc,
    unsigned short* __restrict__ wf_frag)
{
    const int e = blockIdx.x * 256 + threadIdx.x;      // 8192
    if (e < 4 * 4 * 64 * 8) {
        const int j  = e & 7;
        const int l  = (e >> 3) & 63;
        const int ct = (e >> 9) & 3;
        const int ks = e >> 11;
        const int i  = ks * 32 + (l >> 4) * 8 + j;
        const int c  = ct * 16 + (l & 15);
        float w = Wf[(size_t)i * C_OUTC + c];
        if (i < C_OUTC) w *= sc[i];
        wf_frag[e] = f2b(w);
    }
}

// ---------------------------------------------------------------------------
// Fused BN+ReLU+concat+linear via MFMA, in-place on y.
// Block = 128 rows x 4 waves (wave w owns rows w*32..w*32+31). Stage
// A = concat(max(y,nb), skip) as bf16 into LDS (272B-padded rows), then
// 32 MFMA/wave against the BN-folded Wf fragments; acc seeded with bias.
// In-place safe: all y reads complete before the post-staging barrier.
// ---------------------------------------------------------------------------
__global__ __launch_bounds__(256) void fuse_mfma(
    float* __restrict__ y, const float* __restrict__ skip,
    const unsigned short* __restrict__ wf_frag, const float* __restrict__ sc)
{
    __shared__ __align__(16) unsigned short alds[128 * 136];   // 34 KB
    const int rb = blockIdx.x * 128;
    const float4* __restrict__ y4 = (const float4*)(y + (size_t)rb * C_OUTC);
    const float4* __restrict__ s4 = (const float4*)(skip + (size_t)rb * C_SKIP);
    const float4* __restrict__ nb4p = (const float4*)(sc + C_OUTC);

    for (int e = threadIdx.x; e < 128 * 32; e += 256) {
        const int row = e >> 5, q = e & 31;
        float4 v;
        if (q < 16) {
            v = y4[row * 16 + q];
            const float4 nb = nb4p[q];
            v.x = fmaxf(v.x, nb.x); v.y = fmaxf(v.y, nb.y);
            v.z = fmaxf(v.z, nb.z); v.w = fmaxf(v.w, nb.w);
        } else {
            v = s4[row * 16 + (q - 16)];
        }
        uint2 p;
        p.x = f2b(v.x) | ((unsigned)f2b(v.y) << 16);
        p.y = f2b(v.z) | ((unsigned)f2b(v.w) << 16);
        *(uint2*)(&alds[row * 136 + q * 4]) = p;
    }
    __syncthreads();

    const int w   = threadIdx.x >> 6;          // wave 0..3
    const int l   = threadIdx.x & 63;
    const int r16 = l & 15, hi = l >> 4;
    const int rw  = w * 32;

    f32x4 acc[2][4];
    #pragma unroll
    for (int ct = 0; ct < 4; ++ct) {
        const float b0 = sc[2 * C_OUTC + ct * 16 + r16];
        acc[0][ct] = (f32x4){b0, b0, b0, b0};
        acc[1][ct] = (f32x4){b0, b0, b0, b0};
    }

    #pragma unroll
    for (int ks = 0; ks < 4; ++ks) {
        const bf16x8 a0 = *(const bf16x8*)(&alds[(rw + r16) * 136 + ks * 32 + hi * 8]);
        const bf16x8 a1 = *(const bf16x8*)(&alds[(rw + 16 + r16) * 136 + ks * 32 + hi * 8]);
        #pragma unroll
        for (int ct = 0; ct < 4; ++ct) {
            const bf16x8 b = *(const bf16x8*)(wf_frag + ((ks * 4 + ct) * 64 + l) * 8);
            acc[0][ct] = __builtin_amdgcn_mfma_f32_16x16x32_bf16(a0, b, acc[0][ct], 0, 0, 0);
            acc[1][ct] = __builtin_amdgcn_mfma_f32_16x16x32_bf16(a1, b, acc[1][ct], 0, 0, 0);
        }
    }

    #pragma unroll
    for (int rt = 0; rt < 2; ++rt)
        #pragma unroll
        for (int ct = 0; ct < 4; ++ct)
            #pragma unroll
            for (int j = 0; j < 4; ++j)
                y[(size_t)(rb + rw + rt * 16 + hi * 4 + j) * C_OUTC + ct * 16 + r16]
                    = acc[rt][ct][j];
}

// ---------------------------------------------------------------------------
extern "C" void kernel_launch(void* const* d_in, const int* in_sizes, int n_in,
                              void* d_out, int out_size, void* d_ws, size_t ws_size,
                              hipStream_t stream)
{
    const float* x      = (const float*)d_in[0];
    const float* skip   = (const float*)d_in[1];
    const float* Wd     = (const float*)d_in[2];
    const float* gamma  = (const float*)d_in[3];
    const float* beta   = (const float*)d_in[4];
    const float* Wf     = (const float*)d_in[5];
    const int*   in_idx  = (const int*)d_in[6];
    const int*   out_idx = (const int*)d_in[7];

    float* y     = (float*)d_out;            // y lives in d_out (same shape)
    float* stats = (float*)d_ws;             // 128 floats: sum | sumsq
    float* sc    = stats + 128;              // 192 floats: s | -b/s | bias

    unsigned short* xb      = (unsigned short*)((char*)d_ws + 4096);   // 25.6 MB
    unsigned short* bfrag   = xb + (size_t)N_IN * C_IN;                // 128 KB
    unsigned short* wf_frag = bfrag + (size_t)KK * 8192;               // 16 KB
    const size_t zoff = 4096 + (size_t)N_IN * C_IN * 2 + KK * 8192 * 2 + 8192 * 2;
    float* z = (float*)((char*)d_ws + zoff);

    const size_t zbytes_per_k = (size_t)N_IN * C_OUTC * sizeof(float);
    int kc = (ws_size > zoff) ? (int)((ws_size - zoff) / zbytes_per_k) : 1;
    if (kc > KK) kc = KK;
    if (kc < 1)  kc = 1;

    hipMemsetAsync(d_out, 0, (size_t)N_OUT * C_OUTC * sizeof(float), stream);
    hipMemsetAsync(d_ws, 0, 128 * sizeof(float), stream);

    xcast<<<(N_IN * C_IN / 8 + 255) / 256, 256, 0, stream>>>((const float4*)x, xb);
    prep_bfrag<<<(KK * 8192 + 255) / 256, 256, 0, stream>>>(Wd, bfrag);

    for (int k0 = 0; k0 < KK; k0 += kc) {
        const int c = (k0 + kc <= KK) ? kc : (KK - k0);
        dim3 ggrid(N_IN / 32, (c + 3) / 4, 1);
        gemm_mfma<<<ggrid, 256, 0, stream>>>(xb, bfrag, z, k0, c);
        scatter_add<<<2048, 256, 0, stream>>>(z, in_idx, out_idx, y, k0, c);
    }

    stats_kernel<<<2048, 256, 0, stream>>>(y, stats);
    finalize_kernel<<<1, 64, 0, stream>>>(stats, gamma, beta, Wf, sc);
    prep_ffrag<<<32, 256, 0, stream>>>(Wf, sc, wf_frag);
    fuse_mfma<<<N_OUT / 128, 256, 0, stream>>>(y, skip, wf_frag, sc);
}